// Round 6
// baseline (715.079 us; speedup 1.0000x reference)
//
#include <hip/hip_runtime.h>

#define B_ 32
#define T_ 400
#define C_ 3000
#define SN_ 128
#define SD_ 512
#define DEN_WGS 16         // 2 batches per den workgroup
#define LNS 8.94637462f    // ln(64*120)
#define LN120 4.78749174f  // ln(120)
#define SPAN 80            // byte stride between 64-byte spans in LDS (bank spread)

__device__ __forceinline__ float clip30(float v) { return fminf(30.f, fmaxf(-30.f, v)); }

__device__ __forceinline__ int dot4i8(unsigned a, unsigned b, int c) {
#if __has_builtin(__builtin_amdgcn_sdot4)
    return __builtin_amdgcn_sdot4((int)a, (int)b, c, false);
#else
    return c + (int)(a & 0xff) * (int)(b & 0xff)
             + (int)((a >> 8) & 0xff) * (int)((b >> 8) & 0xff)
             + (int)((a >> 16) & 0xff) * (int)((b >> 16) & 0xff)
             + (int)((a >> 24) & 0xff) * (int)((b >> 24) & 0xff);
#endif
}

template <int CTRL>
__device__ __forceinline__ int dpp_i(int v) {
    return __builtin_amdgcn_update_dpp(v, v, CTRL, 0xF, 0xF, false);
}
template <int CTRL>
__device__ __forceinline__ float fmaxdpp(float v) {
    int mv = __builtin_amdgcn_update_dpp(__float_as_int(v), __float_as_int(v), CTRL, 0xF, 0xF, false);
    return fmaxf(v, __int_as_float(mv));
}
template <int CTRL>
__device__ __forceinline__ float faddpp(float v) {
    int mv = __builtin_amdgcn_update_dpp(__float_as_int(v), __float_as_int(v), CTRL, 0xF, 0xF, false);
    return v + __int_as_float(mv);
}
// a += partner-lane's b; quad_perm xor1=0xB1 xor2=0x4E; 0x12n = xor_n (gfx950, proven R2)
template <int CTRL>
__device__ __forceinline__ float fxaddf(float a, float b) {
    int t = __builtin_amdgcn_update_dpp(__float_as_int(b), __float_as_int(b), CTRL, 0xF, 0xF, false);
    return a + __int_as_float(t);
}
__device__ __forceinline__ float swz16f(float v) {
    return __int_as_float(__builtin_amdgcn_ds_swizzle(__float_as_int(v), 0x401F));
}
// wave-wide max, VALU-only: 4 xor-DPP stages + 4 readlanes + 3 maxes. (proven R3)
__device__ __forceinline__ float wavemax_fast(float v) {
    v = fmaxdpp<0x121>(v); v = fmaxdpp<0x122>(v);
    v = fmaxdpp<0x124>(v); v = fmaxdpp<0x128>(v);
    float a = __int_as_float(__builtin_amdgcn_readlane(__float_as_int(v), 0));
    float b = __int_as_float(__builtin_amdgcn_readlane(__float_as_int(v), 16));
    float c = __int_as_float(__builtin_amdgcn_readlane(__float_as_int(v), 32));
    float d = __int_as_float(__builtin_amdgcn_readlane(__float_as_int(v), 48));
    return fmaxf(fmaxf(a, b), fmaxf(c, d));
}
__device__ __forceinline__ float waveallsum(float v) {
    v = faddpp<0x121>(v); v = faddpp<0x122>(v);
    v = faddpp<0x124>(v); v = faddpp<0x128>(v);
    v = v + swz16f(v);
    v = v + __shfl_xor(v, 32, 64);
    return v;
}
// workgroup barrier with LDS-only drain (keeps em prefetch in flight). (proven R4)
__device__ __forceinline__ void barrier_lds() {
    asm volatile("s_waitcnt lgkmcnt(0)\n\ts_barrier" ::: "memory");
}

// 8 partial dots over one 64B activation span vs the thread's 128-dword tq,
// scaled by e_own, then select-free XOR-DPP butterfly fold -> full dot for
// the thread's state. Builtin dot4 (R4-proven numerics).
__device__ __forceinline__ float span_dot_fold(const unsigned* tq,
                                               uint4 e0, uint4 e1, uint4 e2, uint4 e3,
                                               float e_own) {
    int ac0, ac1, ac2, ac3, ac4, ac5, ac6, ac7;
    #define DOTD0(W, I) \
        ac0 = dot4i8((W), tq[(I)],       0); \
        ac1 = dot4i8((W), tq[16 + (I)],  0); \
        ac2 = dot4i8((W), tq[32 + (I)],  0); \
        ac3 = dot4i8((W), tq[48 + (I)],  0); \
        ac4 = dot4i8((W), tq[64 + (I)],  0); \
        ac5 = dot4i8((W), tq[80 + (I)],  0); \
        ac6 = dot4i8((W), tq[96 + (I)],  0); \
        ac7 = dot4i8((W), tq[112 + (I)], 0);
    #define DOTD(W, I) \
        ac0 = dot4i8((W), tq[(I)],       ac0); \
        ac1 = dot4i8((W), tq[16 + (I)],  ac1); \
        ac2 = dot4i8((W), tq[32 + (I)],  ac2); \
        ac3 = dot4i8((W), tq[48 + (I)],  ac3); \
        ac4 = dot4i8((W), tq[64 + (I)],  ac4); \
        ac5 = dot4i8((W), tq[80 + (I)],  ac5); \
        ac6 = dot4i8((W), tq[96 + (I)],  ac6); \
        ac7 = dot4i8((W), tq[112 + (I)], ac7);
    DOTD0(e0.x, 0) DOTD(e0.y, 1)  DOTD(e0.z, 2)  DOTD(e0.w, 3)
    DOTD(e1.x, 4)  DOTD(e1.y, 5)  DOTD(e1.z, 6)  DOTD(e1.w, 7)
    DOTD(e2.x, 8)  DOTD(e2.y, 9)  DOTD(e2.z, 10) DOTD(e2.w, 11)
    DOTD(e3.x, 12) DOTD(e3.y, 13) DOTD(e3.z, 14) DOTD(e3.w, 15)
    #undef DOTD
    #undef DOTD0
    float f0 = (float)ac0 * e_own, f1 = (float)ac1 * e_own;
    float f2 = (float)ac2 * e_own, f3 = (float)ac3 * e_own;
    float f4 = (float)ac4 * e_own, f5 = (float)ac5 * e_own;
    float f6 = (float)ac6 * e_own, f7 = (float)ac7 * e_own;
    f0 = fxaddf<0xB1>(f0, f1);  f2 = fxaddf<0xB1>(f2, f3);
    f4 = fxaddf<0xB1>(f4, f5);  f6 = fxaddf<0xB1>(f6, f7);
    f0 = fxaddf<0x4E>(f0, f2);  f4 = fxaddf<0x4E>(f4, f6);
    f0 = fxaddf<0x124>(f0, f4);
    return f0;
}

// prep: unchanged layout (R1+). [0,65536) tp8 dot4 layout; then em_den; then em_num.
__global__ void prep(const float* __restrict__ dt, unsigned* __restrict__ tp8,
                     const float* __restrict__ x, const int* __restrict__ den_pdf,
                     const int* __restrict__ num_pdf,
                     float* __restrict__ em_den, float* __restrict__ em_num) {
    size_t id = (size_t)blockIdx.x * 1024 + threadIdx.x;
    if (id < 65536) {
        int o = (int)id;
        int b4 = o & 3, tid = (o >> 2) & 511, k = o >> 11;
        int r = 4 * k + b4;
        int m = r >> 4, i = r & 15;
        int g = tid >> 3, j = tid & 7;
        int s_out = 8 * g + (m ^ j);
        int s_from0 = 64 * j + 4 * i;
        unsigned wv = 0;
        #pragma unroll
        for (int by = 0; by < 4; ++by) {
            float e = __expf(dt[(s_from0 + by) * SD_ + s_out]);
            int pq = __float2int_rn(e * 64.f);
            if (pq > 127) pq = 127;
            wv |= (unsigned)pq << (8 * by);
        }
        tp8[o] = wv;
    } else if (id < 65536 + 6553600) {
        size_t e = id - 65536;
        int s = (int)(e & 511);
        size_t bt = e >> 9;                    // b*400 + t
        em_den[e] = clip30(x[bt * C_ + den_pdf[s]]);
    } else if (id < 65536 + 6553600 + 1638400) {
        size_t e = id - 65536 - 6553600;
        int s = (int)(e & 127);
        size_t bt = e >> 7;
        int b = (int)(bt / 400);
        em_num[e] = clip30(x[bt * C_ + num_pdf[b * SN_ + s]]);
    }
}

__global__ __launch_bounds__(512, 2)
void fwd_kernel(const int* __restrict__ seqlen,
                const float* __restrict__ num_trans,
                const float* __restrict__ num_init, const float* __restrict__ num_final,
                const unsigned* __restrict__ tp8,
                const float* __restrict__ den_init, const float* __restrict__ den_final,
                const float* __restrict__ em_den, const float* __restrict__ em_num,
                float* __restrict__ parts) {
    const int tid = threadIdx.x;

    if (blockIdx.x < DEN_WGS) {
        // ---- denominator: TWO batches per WG sharing the same tq registers.
        // Two independent dot-blocks + two independent tails per step: the
        // serial tail / LDS-latency stall is paid once per 2 batches. ----
        __shared__ __align__(16) unsigned char ea[2][2][8 * SPAN];  // [buf][batch][spans]
        __shared__ float Ms[2][2][8];                               // [buf][batch][wave]
        __shared__ float fr[2][8];
        const int b0 = 2 * blockIdx.x, b1 = b0 + 1;
        const int L0 = seqlen[b0], L1 = seqlen[b1];
        const int Lmax = (L0 > L1) ? L0 : L1;
        const int w = tid >> 6, l = tid & 63;   // wave, lane
        const int j = tid & 7;                  // source span (0..7)

        // trans: slot m, dword i -> tq[16m+i] = T8[64j+4i+b, 8g+(m^j)] (shared by both batches)
        unsigned tq[128];
        {
            const uint4* tg = (const uint4*)tp8;
            #pragma unroll
            for (int i = 0; i < 32; ++i) {
                uint4 v = tg[(i << 9) + tid];
                tq[4 * i + 0] = v.x;
                tq[4 * i + 1] = v.y;
                tq[4 * i + 2] = v.z;
                tq[4 * i + 3] = v.w;
            }
        }

        const float* emp0 = em_den + (size_t)b0 * T_ * SD_ + tid;
        const float* emp1 = em_den + (size_t)b1 * T_ * SD_ + tid;

        // t = 0 for both batches
        float dini = den_init[tid];
        float a0 = dini + emp0[0];
        float a1 = dini + emp1[0];
        float ms0 = wavemax_fast(a0);
        float ms1 = wavemax_fast(a1);
        int un0 = __float2int_rn(fminf(120.f * __expf(a0 - ms0), 127.f));
        int un1 = __float2int_rn(fminf(120.f * __expf(a1 - ms1), 127.f));
        {
            int u0 = un0, u1 = un1;
            u0 |= dpp_i<0xB1>(u0) << 8;  u1 |= dpp_i<0xB1>(u1) << 8;
            u0 |= dpp_i<0x4E>(u0) << 16; u1 |= dpp_i<0x4E>(u1) << 16;
            if ((tid & 3) == 0) {
                *(unsigned*)&ea[0][0][SPAN * w + (tid & 63)] = (unsigned)u0;
                *(unsigned*)&ea[0][1][SPAN * w + (tid & 63)] = (unsigned)u1;
            }
        }
        if (l == 0) { Ms[0][0][w] = ms0; Ms[0][1][w] = ms1; }
        barrier_lds();

        float emA0 = emp0[SD_], emB0 = emp0[2 * SD_];
        float emA1 = emp1[SD_], emB1 = emp1[2 * SD_];
        int cur = 0;
        for (int t = 1; t < Lmax; ++t) {
            int tn = t + 2; if (tn > T_ - 1) tn = T_ - 1;
            float emN0 = emp0[(size_t)tn * SD_];
            float emN1 = emp1[(size_t)tn * SD_];

            float msj0 = Ms[cur][0][j], msj1 = Ms[cur][1][j];
            const uint4* er0 = (const uint4*)&ea[cur][0][SPAN * j];
            const uint4* er1 = (const uint4*)&ea[cur][1][SPAN * j];
            uint4 e0 = er0[0], e1 = er0[1], e2 = er0[2], e3 = er0[3];
            uint4 d0 = er1[0], d1 = er1[1], d2 = er1[2], d3 = er1[3];

            float F0 = span_dot_fold(tq, e0, e1, e2, e3, __expf(msj0 - ms0));
            float F1 = span_dot_fold(tq, d0, d1, d2, d3, __expf(msj1 - ms1));

            // two independent tails (compiler interleaves; ILP-2 on the dep chains)
            float g0 = fmaf(0.69314718f,
                            (float)__float_as_int(F0) * 1.1920929e-7f - 127.0f, emA0);
            float g1 = fmaf(0.69314718f,
                            (float)__float_as_int(F1) * 1.1920929e-7f - 127.0f, emA1);
            float gg0 = wavemax_fast(g0);
            float gg1 = wavemax_fast(g1);
            int nun0 = __float2int_rn(fminf(120.f * F0 * __expf(emA0 - gg0), 127.f));
            int nun1 = __float2int_rn(fminf(120.f * F1 * __expf(emA1 - gg1), 127.f));
            if (t < L0) { un0 = nun0; ms0 = ms0 + gg0 - LNS; }
            if (t < L1) { un1 = nun1; ms1 = ms1 + gg1 - LNS; }
            {
                int u0 = un0, u1 = un1;
                u0 |= dpp_i<0xB1>(u0) << 8;  u1 |= dpp_i<0xB1>(u1) << 8;
                u0 |= dpp_i<0x4E>(u0) << 16; u1 |= dpp_i<0x4E>(u1) << 16;
                if ((tid & 3) == 0) {
                    *(unsigned*)&ea[cur ^ 1][0][SPAN * w + (tid & 63)] = (unsigned)u0;
                    *(unsigned*)&ea[cur ^ 1][1][SPAN * w + (tid & 63)] = (unsigned)u1;
                }
            }
            if (l == 0) { Ms[cur ^ 1][0][w] = ms0; Ms[cur ^ 1][1][w] = ms1; }
            emA0 = emB0; emB0 = emN0;
            emA1 = emB1; emB1 = emN1;
            barrier_lds();              // single barrier/step, LDS-drain only
            cur ^= 1;
        }

        // final for both batches: alpha(s) = log(u_s) + Ms - ln120
        float dfin = den_final[tid];
        float mm0 = Ms[cur][0][0], mm1 = Ms[cur][1][0];
        #pragma unroll
        for (int k2 = 1; k2 < 8; ++k2) {
            mm0 = fmaxf(mm0, Ms[cur][0][k2]);
            mm1 = fmaxf(mm1, Ms[cur][1][k2]);
        }
        float fv0 = (float)un0 * __expf(dfin + (ms0 - mm0));
        float fv1 = (float)un1 * __expf(dfin + (ms1 - mm1));
        fv0 = waveallsum(fv0);
        fv1 = waveallsum(fv1);
        if (l == 0) { fr[0][w] = fv0; fr[1][w] = fv1; }
        __syncthreads();
        if (tid == 0) {
            float t0 = 0.f, t1 = 0.f;
            for (int i = 0; i < 8; ++i) { t0 += fr[0][i]; t1 += fr[1][i]; }
            parts[B_ + b0] = mm0 + __logf(t0) - LN120;
            parts[B_ + b1] = mm1 + __logf(t1) - LN120;
        }
    } else {
        // ---- numerator: 4 banded 128-state chains per 512-thread WG
        //      (R1-proven path; double-buffered -> 1 barrier/step) ----
        __shared__ float aLn[2][4][SN_];
        __shared__ float nredn[4][2];
        const int nb = blockIdx.x - DEN_WGS;          // 0..7
        const int lb = tid >> 7;                      // local batch 0..3
        const int b  = nb * 4 + lb;
        const int s  = tid & 127;
        const int L  = seqlen[b];
        const int lane = tid & 63;
        const int wv2 = (tid >> 6) & 1;
        const float* ep = em_num + (size_t)b * T_ * SN_ + s;
        const float tself = num_trans[((size_t)b * SN_ + s) * SN_ + s];
        const float tup = (s > 0) ? num_trans[((size_t)b * SN_ + (s - 1)) * SN_ + s] : 0.f;
        float alpha = num_init[b * SN_ + s] + ep[0];
        aLn[0][lb][s] = alpha;
        __syncthreads();
        float emA = ep[SN_], emB = ep[2 * SN_];
        int cur = 0;
        for (int t = 1; t < T_; ++t) {
            int tt = t + 2; if (tt > T_ - 1) tt = T_ - 1;
            float emN = ep[(size_t)tt * SN_];
            bool live = (t < L);
            float yy = alpha + tself;
            float newa;
            if (s > 0) {
                float xx = aLn[cur][lb][s - 1] + tup;
                float mx = fmaxf(xx, yy), mn = fminf(xx, yy);
                newa = mx + log1pf(__expf(mn - mx)) + emA;
            } else {
                newa = yy + emA;
            }
            if (live) alpha = newa;
            aLn[cur ^ 1][lb][s] = alpha;
            emA = emB; emB = emN;
            __syncthreads();
            cur ^= 1;
        }
        float v = alpha + num_final[b * SN_ + s];
        float wm = v;
        #pragma unroll
        for (int o = 32; o; o >>= 1) wm = fmaxf(wm, __shfl_xor(wm, o, 64));
        if (lane == 0) nredn[lb][wv2] = wm;
        __syncthreads();
        float fm = fmaxf(nredn[lb][0], nredn[lb][1]);
        __syncthreads();
        float pe = __expf(v - fm);
        #pragma unroll
        for (int o = 32; o; o >>= 1) pe += __shfl_xor(pe, o, 64);
        if (lane == 0) nredn[lb][wv2] = pe;
        __syncthreads();
        if (s == 0) parts[b] = fm + __logf(nredn[lb][0] + nredn[lb][1]);
    }
}

__global__ void finish(const float* __restrict__ parts, float* __restrict__ out) {
    int lane = threadIdx.x;   // 64 threads, 1 wave
    float v = (lane < B_) ? (parts[B_ + lane] - parts[lane]) : 0.f;
    #pragma unroll
    for (int o = 32; o; o >>= 1) v += __shfl_xor(v, o, 64);
    if (lane == 0) out[0] = v;   // loss = sum(den) - sum(num)
}

extern "C" void kernel_launch(void* const* d_in, const int* in_sizes, int n_in,
                              void* d_out, int out_size, void* d_ws, size_t ws_size,
                              hipStream_t stream) {
    const float* x         = (const float*)d_in[0];
    const int*   seqlen    = (const int*)d_in[1];
    const float* num_trans = (const float*)d_in[2];
    const int*   num_pdf   = (const int*)d_in[3];
    const float* num_init  = (const float*)d_in[4];
    const float* num_final = (const float*)d_in[5];
    const float* den_trans = (const float*)d_in[6];
    const int*   den_pdf   = (const int*)d_in[7];
    const float* den_init  = (const float*)d_in[8];
    const float* den_final = (const float*)d_in[9];
    float* out   = (float*)d_out;
    float* parts = (float*)d_ws;                                  // 64 floats
    unsigned* tp8 = (unsigned*)((char*)d_ws + 4096);              // 256 KB i8 packed trans
    float* em_den = (float*)((char*)d_ws + 4096 + 262144);        // 26.2 MB
    float* em_num = em_den + 6553600;                             // 6.5 MB

    prep<<<8064, 1024, 0, stream>>>(den_trans, tp8, x, den_pdf, num_pdf, em_den, em_num);
    fwd_kernel<<<DEN_WGS + 8, 512, 0, stream>>>(seqlen, num_trans, num_init, num_final,
                                                tp8, den_init, den_final, em_den, em_num, parts);
    finish<<<1, 64, 0, stream>>>(parts, out);
}

// Round 7
// 409.199 us; speedup vs baseline: 1.7475x; 1.7475x over previous
//
#include <hip/hip_runtime.h>

#define B_ 32
#define T_ 400
#define C_ 3000
#define SN_ 128
#define SD_ 512
#define LNS 8.94637462f    // ln(64*120)
#define LN120 4.78749174f  // ln(120)
#define SPAN 80            // byte stride between 64-byte spans in LDS (bank spread)

__device__ __forceinline__ float clip30(float v) { return fminf(30.f, fmaxf(-30.f, v)); }

__device__ __forceinline__ int dot4i8(unsigned a, unsigned b, int c) {
#if __has_builtin(__builtin_amdgcn_sdot4)
    return __builtin_amdgcn_sdot4((int)a, (int)b, c, false);
#else
    return c + (int)(a & 0xff) * (int)(b & 0xff)
             + (int)((a >> 8) & 0xff) * (int)((b >> 8) & 0xff)
             + (int)((a >> 16) & 0xff) * (int)((b >> 16) & 0xff)
             + (int)((a >> 24) & 0xff) * (int)((b >> 24) & 0xff);
#endif
}

template <int CTRL>
__device__ __forceinline__ int dpp_i(int v) {
    return __builtin_amdgcn_update_dpp(v, v, CTRL, 0xF, 0xF, false);
}
template <int CTRL>
__device__ __forceinline__ float fmaxdpp(float v) {
    int mv = __builtin_amdgcn_update_dpp(__float_as_int(v), __float_as_int(v), CTRL, 0xF, 0xF, false);
    return fmaxf(v, __int_as_float(mv));
}
template <int CTRL>
__device__ __forceinline__ float faddpp(float v) {
    int mv = __builtin_amdgcn_update_dpp(__float_as_int(v), __float_as_int(v), CTRL, 0xF, 0xF, false);
    return v + __int_as_float(mv);
}
// a += partner-lane's b; quad_perm xor1=0xB1 xor2=0x4E; 0x12n = xor_n (gfx950, proven R2)
template <int CTRL>
__device__ __forceinline__ float fxaddf(float a, float b) {
    int t = __builtin_amdgcn_update_dpp(__float_as_int(b), __float_as_int(b), CTRL, 0xF, 0xF, false);
    return a + __int_as_float(t);
}
__device__ __forceinline__ float swz16f(float v) {
    return __int_as_float(__builtin_amdgcn_ds_swizzle(__float_as_int(v), 0x401F));
}
// wave-wide max, VALU-only: 4 xor-DPP stages (per-16-row max) + 4 readlanes + 3 maxes.
// Result uniform across the wave. (proven R3)
__device__ __forceinline__ float wavemax_fast(float v) {
    v = fmaxdpp<0x121>(v); v = fmaxdpp<0x122>(v);
    v = fmaxdpp<0x124>(v); v = fmaxdpp<0x128>(v);
    float a = __int_as_float(__builtin_amdgcn_readlane(__float_as_int(v), 0));
    float b = __int_as_float(__builtin_amdgcn_readlane(__float_as_int(v), 16));
    float c = __int_as_float(__builtin_amdgcn_readlane(__float_as_int(v), 32));
    float d = __int_as_float(__builtin_amdgcn_readlane(__float_as_int(v), 48));
    return fmaxf(fmaxf(a, b), fmaxf(c, d));
}
__device__ __forceinline__ float waveallsum(float v) {
    v = faddpp<0x121>(v); v = faddpp<0x122>(v);
    v = faddpp<0x124>(v); v = faddpp<0x128>(v);
    v = v + swz16f(v);
    v = v + __shfl_xor(v, 32, 64);
    return v;
}
// workgroup barrier with LDS-only drain: skips the conservative vmcnt(0) drain
// __syncthreads() emits, so the 2-step-ahead em prefetch stays in flight. (proven R4)
__device__ __forceinline__ void barrier_lds() {
    asm volatile("s_waitcnt lgkmcnt(0)\n\ts_barrier" ::: "memory");
}

// prep:
//  [0,65536) dwords: exp(den_trans) i8 (scale 64) in the per-thread dot4 layout
//    for the 8-lane-span decomposition.
//    dword o: b4=o&3, tid=(o>>2)&511, k=o>>11; reg r=4k+b4; slot m=r>>4, i=r&15;
//    g=tid>>3, j=tid&7; s_out = 8g + (m^j)  (XOR-slot for select-free butterfly);
//    bytes: s_from = 64j + 4i + by.
//    fwd reads uint4 #k at tg[(k<<9)+tid] -> tq[4k+b4]=dword o.
//  [65536,+6553600) em_den[b][t][s] pre-clipped; then em_num[b][t][s].
__global__ void prep(const float* __restrict__ dt, unsigned* __restrict__ tp8,
                     const float* __restrict__ x, const int* __restrict__ den_pdf,
                     const int* __restrict__ num_pdf,
                     float* __restrict__ em_den, float* __restrict__ em_num) {
    size_t id = (size_t)blockIdx.x * 1024 + threadIdx.x;
    if (id < 65536) {
        int o = (int)id;
        int b4 = o & 3, tid = (o >> 2) & 511, k = o >> 11;
        int r = 4 * k + b4;
        int m = r >> 4, i = r & 15;
        int g = tid >> 3, j = tid & 7;
        int s_out = 8 * g + (m ^ j);
        int s_from0 = 64 * j + 4 * i;
        unsigned wv = 0;
        #pragma unroll
        for (int by = 0; by < 4; ++by) {
            float e = __expf(dt[(s_from0 + by) * SD_ + s_out]);
            int pq = __float2int_rn(e * 64.f);
            if (pq > 127) pq = 127;
            wv |= (unsigned)pq << (8 * by);
        }
        tp8[o] = wv;
    } else if (id < 65536 + 6553600) {
        size_t e = id - 65536;
        int s = (int)(e & 511);
        size_t bt = e >> 9;                    // b*400 + t
        em_den[e] = clip30(x[bt * C_ + den_pdf[s]]);
    } else if (id < 65536 + 6553600 + 1638400) {
        size_t e = id - 65536 - 6553600;
        int s = (int)(e & 127);
        size_t bt = e >> 7;
        int b = (int)(bt / 400);
        em_num[e] = clip30(x[bt * C_ + num_pdf[b * SN_ + s]]);
    }
}

// __launch_bounds__(512,1): we only ever place 1 WG/CU (40 blocks, 256 CUs),
// so min-waves/EU=1 is truthful and doubles the register budget to 512/thread.
// This removes the pressure that made the allocator park tq[128] in AGPRs
// (VGPR_Count 84 + 128 AGPR under the old (512,2) 256-budget), which cost a
// v_accvgpr_read per dot4 (~580 cyc/SIMD/step, the dominant VALU overhead).
__global__ __launch_bounds__(512, 1)
void fwd_kernel(const int* __restrict__ seqlen,
                const float* __restrict__ num_trans,
                const float* __restrict__ num_init, const float* __restrict__ num_final,
                const unsigned* __restrict__ tp8,
                const float* __restrict__ den_init, const float* __restrict__ den_final,
                const float* __restrict__ em_den, const float* __restrict__ em_num,
                float* __restrict__ parts) {
    const int tid = threadIdx.x;

    if (blockIdx.x < B_) {
        // ---- denominator: one batch/WG, 512 threads, 1 state/thread.
        // Per-wave log-scales Ms[w]; one barrier/step. 8-lane span decomposition;
        // fold is pure XOR-DPP (0xB1, 0x4E, 0x124); wave max is DPP+readlane. ----
        __shared__ __align__(16) unsigned char ea[2][8 * SPAN];   // u8 activations, dbuf
        __shared__ float Ms[2][8];                                // per-wave log scales
        __shared__ float fr[8];
        const int b = blockIdx.x;
        const int L = seqlen[b];
        const int w = tid >> 6, l = tid & 63;   // wave, lane
        const int j = tid & 7;                  // source span (0..7)

        // trans: slot m, dword i -> tq[16m+i] = T8[64j+4i+b, 8g+(m^j)]
        unsigned tq[128];
        {
            const uint4* tg = (const uint4*)tp8;
            #pragma unroll
            for (int i = 0; i < 32; ++i) {
                uint4 v = tg[(i << 9) + tid];
                tq[4 * i + 0] = v.x;
                tq[4 * i + 1] = v.y;
                tq[4 * i + 2] = v.z;
                tq[4 * i + 3] = v.w;
            }
        }

        const float* emp = em_den + (size_t)b * T_ * SD_ + tid;

        // t = 0: alpha0 = init + em0; quantize vs wave-local max
        float a0f = den_init[tid] + emp[0];
        float ms_w = wavemax_fast(a0f);          // own wave's scale, kept in register
        int un = __float2int_rn(fminf(120.f * __expf(a0f - ms_w), 127.f));
        {
            int uu = un;
            uu |= dpp_i<0xB1>(uu) << 8;
            uu |= dpp_i<0x4E>(uu) << 16;
            if ((tid & 3) == 0)
                *(unsigned*)&ea[0][SPAN * w + (tid & 63)] = (unsigned)uu;
        }
        if (l == 0) Ms[0][w] = ms_w;
        barrier_lds();

        float emA = emp[SD_], emB = emp[2 * SD_];
        int cur = 0;
        for (int t = 1; t < L; ++t) {
            int tn = (t + 2 < L) ? t + 2 : L - 1;
            float emN = emp[(size_t)tn * SD_];

            float ms_j = Ms[cur][j];            // source span's scale (LDS; own in reg)
            const uint4* er = (const uint4*)&ea[cur][SPAN * j];
            uint4 e0 = er[0], e1 = er[1], e2 = er[2], e3 = er[3];

            // accumulators initialized by the first dot (c = 0)
            int ac0, ac1, ac2, ac3, ac4, ac5, ac6, ac7;
            #define DOTD0(W, I) \
                ac0 = dot4i8((W), tq[(I)],       0); \
                ac1 = dot4i8((W), tq[16 + (I)],  0); \
                ac2 = dot4i8((W), tq[32 + (I)],  0); \
                ac3 = dot4i8((W), tq[48 + (I)],  0); \
                ac4 = dot4i8((W), tq[64 + (I)],  0); \
                ac5 = dot4i8((W), tq[80 + (I)],  0); \
                ac6 = dot4i8((W), tq[96 + (I)],  0); \
                ac7 = dot4i8((W), tq[112 + (I)], 0);
            #define DOTD(W, I) \
                ac0 = dot4i8((W), tq[(I)],       ac0); \
                ac1 = dot4i8((W), tq[16 + (I)],  ac1); \
                ac2 = dot4i8((W), tq[32 + (I)],  ac2); \
                ac3 = dot4i8((W), tq[48 + (I)],  ac3); \
                ac4 = dot4i8((W), tq[64 + (I)],  ac4); \
                ac5 = dot4i8((W), tq[80 + (I)],  ac5); \
                ac6 = dot4i8((W), tq[96 + (I)],  ac6); \
                ac7 = dot4i8((W), tq[112 + (I)], ac7);
            DOTD0(e0.x, 0) DOTD(e0.y, 1)  DOTD(e0.z, 2)  DOTD(e0.w, 3)
            DOTD(e1.x, 4)  DOTD(e1.y, 5)  DOTD(e1.z, 6)  DOTD(e1.w, 7)
            DOTD(e2.x, 8)  DOTD(e2.y, 9)  DOTD(e2.z, 10) DOTD(e2.w, 11)
            DOTD(e3.x, 12) DOTD(e3.y, 13) DOTD(e3.z, 14) DOTD(e3.w, 15)
            #undef DOTD
            #undef DOTD0

            // scale by own span's factor, then select-free XOR butterfly fold (all DPP)
            float e_own = __expf(ms_j - ms_w);
            float f0 = (float)ac0 * e_own, f1 = (float)ac1 * e_own;
            float f2 = (float)ac2 * e_own, f3 = (float)ac3 * e_own;
            float f4 = (float)ac4 * e_own, f5 = (float)ac5 * e_own;
            float f6 = (float)ac6 * e_own, f7 = (float)ac7 * e_own;
            f0 = fxaddf<0xB1>(f0, f1);  f2 = fxaddf<0xB1>(f2, f3);
            f4 = fxaddf<0xB1>(f4, f5);  f6 = fxaddf<0xB1>(f6, f7);
            f0 = fxaddf<0x4E>(f0, f2);  f4 = fxaddf<0x4E>(f4, f6);
            f0 = fxaddf<0x124>(f0, f4); // xor4 via DPP (proven on gfx950 by R2)

            // approx ln via float bits (underestimates <=0.06 nats; moves quant point only)
            float g = fmaf(0.69314718f,
                           (float)__float_as_int(f0) * 1.1920929e-7f - 127.0f, emA);
            float gg = wavemax_fast(g);          // VALU-only wave max
            un = __float2int_rn(fminf(120.f * f0 * __expf(emA - gg), 127.f));
            {
                int uu = un;
                uu |= dpp_i<0xB1>(uu) << 8;
                uu |= dpp_i<0x4E>(uu) << 16;
                if ((tid & 3) == 0)
                    *(unsigned*)&ea[cur ^ 1][SPAN * w + (tid & 63)] = (unsigned)uu;
            }
            ms_w = gg + ms_w - LNS;              // own next-step scale, stays in register
            if (l == 0) Ms[cur ^ 1][w] = ms_w;
            emA = emB; emB = emN;
            barrier_lds();              // single barrier/step, LDS-drain only
            cur ^= 1;
        }

        // final: alpha(s) = log(u_s) + Ms[w(s)] - ln120
        float mm = Ms[cur][0];
        #pragma unroll
        for (int k2 = 1; k2 < 8; ++k2) mm = fmaxf(mm, Ms[cur][k2]);
        float fv = (float)un * __expf(den_final[tid] + (ms_w - mm));
        fv = waveallsum(fv);
        if (l == 0) fr[w] = fv;
        __syncthreads();
        if (tid == 0) {
            float tot = 0.f;
            for (int i = 0; i < 8; ++i) tot += fr[i];
            parts[B_ + b] = mm + __logf(tot) - LN120;
        }
    } else {
        // ---- numerator: 4 banded 128-state chains per 512-thread WG
        //      (R1-proven path; double-buffered -> 1 barrier/step) ----
        __shared__ float aLn[2][4][SN_];
        __shared__ float nredn[4][2];
        const int nb = blockIdx.x - B_;               // 0..7
        const int lb = tid >> 7;                      // local batch 0..3
        const int b  = nb * 4 + lb;
        const int s  = tid & 127;
        const int L  = seqlen[b];
        const int lane = tid & 63;
        const int wv2 = (tid >> 6) & 1;
        const float* ep = em_num + (size_t)b * T_ * SN_ + s;
        const float tself = num_trans[((size_t)b * SN_ + s) * SN_ + s];
        const float tup = (s > 0) ? num_trans[((size_t)b * SN_ + (s - 1)) * SN_ + s] : 0.f;
        float alpha = num_init[b * SN_ + s] + ep[0];
        aLn[0][lb][s] = alpha;
        __syncthreads();
        float emA = ep[SN_], emB = ep[2 * SN_];
        int cur = 0;
        for (int t = 1; t < T_; ++t) {
            int tt = t + 2; if (tt > T_ - 1) tt = T_ - 1;
            float emN = ep[(size_t)tt * SN_];
            bool live = (t < L);
            float yy = alpha + tself;
            float newa;
            if (s > 0) {
                float xx = aLn[cur][lb][s - 1] + tup;
                float mx = fmaxf(xx, yy), mn = fminf(xx, yy);
                newa = mx + log1pf(__expf(mn - mx)) + emA;
            } else {
                newa = yy + emA;
            }
            if (live) alpha = newa;
            aLn[cur ^ 1][lb][s] = alpha;
            emA = emB; emB = emN;
            __syncthreads();
            cur ^= 1;
        }
        float v = alpha + num_final[b * SN_ + s];
        float wm = v;
        #pragma unroll
        for (int o = 32; o; o >>= 1) wm = fmaxf(wm, __shfl_xor(wm, o, 64));
        if (lane == 0) nredn[lb][wv2] = wm;
        __syncthreads();
        float fm = fmaxf(nredn[lb][0], nredn[lb][1]);
        __syncthreads();
        float pe = __expf(v - fm);
        #pragma unroll
        for (int o = 32; o; o >>= 1) pe += __shfl_xor(pe, o, 64);
        if (lane == 0) nredn[lb][wv2] = pe;
        __syncthreads();
        if (s == 0) parts[b] = fm + __logf(nredn[lb][0] + nredn[lb][1]);
    }
}

__global__ void finish(const float* __restrict__ parts, float* __restrict__ out) {
    int lane = threadIdx.x;   // 64 threads, 1 wave
    float v = (lane < B_) ? (parts[B_ + lane] - parts[lane]) : 0.f;
    #pragma unroll
    for (int o = 32; o; o >>= 1) v += __shfl_xor(v, o, 64);
    if (lane == 0) out[0] = v;   // loss = sum(den) - sum(num)
}

extern "C" void kernel_launch(void* const* d_in, const int* in_sizes, int n_in,
                              void* d_out, int out_size, void* d_ws, size_t ws_size,
                              hipStream_t stream) {
    const float* x         = (const float*)d_in[0];
    const int*   seqlen    = (const int*)d_in[1];
    const float* num_trans = (const float*)d_in[2];
    const int*   num_pdf   = (const int*)d_in[3];
    const float* num_init  = (const float*)d_in[4];
    const float* num_final = (const float*)d_in[5];
    const float* den_trans = (const float*)d_in[6];
    const int*   den_pdf   = (const int*)d_in[7];
    const float* den_init  = (const float*)d_in[8];
    const float* den_final = (const float*)d_in[9];
    float* out   = (float*)d_out;
    float* parts = (float*)d_ws;                                  // 64 floats
    unsigned* tp8 = (unsigned*)((char*)d_ws + 4096);              // 256 KB i8 packed trans
    float* em_den = (float*)((char*)d_ws + 4096 + 262144);        // 26.2 MB
    float* em_num = em_den + 6553600;                             // 6.5 MB

    prep<<<8064, 1024, 0, stream>>>(den_trans, tp8, x, den_pdf, num_pdf, em_den, em_num);
    fwd_kernel<<<40, 512, 0, stream>>>(seqlen, num_trans, num_init, num_final,
                                       tp8, den_init, den_final, em_den, em_num, parts);
    finish<<<1, 64, 0, stream>>>(parts, out);
}